// Round 2
// baseline (717.044 us; speedup 1.0000x reference)
//
#include <hip/hip_runtime.h>
#include <cmath>

static __device__ __forceinline__ float dot4(float4 a, float4 b) {
    return fmaf(a.x, b.x, fmaf(a.y, b.y, fmaf(a.z, b.z, a.w * b.w)));
}

// ---------------- prep: inv-norms + excitability bonus per global neuron ----
// global neuron order: [qk 0..511][fv 512..767][q 768..1279][k(rel) 1280..1791][val 1792..2047]
__global__ void prep_kernel(const float* __restrict__ emb,
                            const float* __restrict__ emb_rel_k,
                            const float* __restrict__ ema_qk,
                            const float* __restrict__ ema_v,
                            const float* __restrict__ ema_rel,
                            const float* __restrict__ ema_val,
                            float* __restrict__ invn,
                            float* __restrict__ bonus)
{
    int n = blockIdx.x * 64 + threadIdx.x;   // grid 32 x 64 -> 2048
    const float* row;
    float ema;
    if (n < 512)       { row = emb + (size_t)n * 64;                ema = ema_qk[n]; }
    else if (n < 768)  { row = emb + (size_t)n * 64;                ema = ema_v[n - 512]; }
    else if (n < 1280) { row = emb + (size_t)n * 64;                ema = ema_rel[n - 768]; }
    else if (n < 1792) { row = emb_rel_k + (size_t)(n - 1280) * 64; ema = ema_rel[n - 1280]; }
    else               { row = emb + (size_t)(n - 512) * 64;        ema = ema_val[n - 1792]; }
    float s = 0.f;
    #pragma unroll
    for (int k = 0; k < 64; k += 4) {
        float4 v = *(const float4*)(row + k);
        s += v.x*v.x + v.y*v.y + v.z*v.z + v.w*v.w;
    }
    invn[n] = 1.0f / sqrtf(s);
    float ex = 1.0f - ema * (1.0f / 1.5f);   // TAU = 1.5
    ex = fminf(fmaxf(ex, 0.f), 1.f);
    bonus[n] = ex * 1.0f;                    // EXC_W = 1.0
}

// ---------------- proj GEMM: h_part[kh] = x[:, kh*1024 + :1024] @ W^T -------
// grid (256 row-tiles, 2 K-halves), 256 threads. Tile: 64 rows x 64 cols.
// Per-thread 4x4 register tile; double-buffered LDS, one barrier per K-chunk.
__launch_bounds__(256)
__global__ void proj_kernel(const float* __restrict__ x,
                            const float* __restrict__ proj_w,
                            float* __restrict__ hpart)
{
    __shared__ float sX[2][64 * 68];
    __shared__ float sW[2][64 * 68];

    const int tid = threadIdx.x;
    const int rowBase = blockIdx.x * 64;
    const int k0 = blockIdx.y * 1024;

    const int cg = tid & 15;        // cols {cg, cg+16, cg+32, cg+48}
    const int rg = tid >> 4;        // rows {rg, rg+16, rg+32, rg+48}
    const int srow = tid >> 4;      // staging: row group
    const int sk4 = tid & 15;       // staging: k-quad

    float acc[4][4];
    #pragma unroll
    for (int i = 0; i < 4; ++i)
        #pragma unroll
        for (int j = 0; j < 4; ++j) acc[i][j] = 0.f;

    float4 rx[4], rw[4];
    // prologue: chunk 0 -> LDS[0]
    #pragma unroll
    for (int i = 0; i < 4; ++i) {
        int row = srow + 16 * i;
        rx[i] = *(const float4*)(x + (size_t)(rowBase + row) * 2048 + k0 + sk4 * 4);
        rw[i] = *(const float4*)(proj_w + (size_t)row * 2048 + k0 + sk4 * 4);
    }
    #pragma unroll
    for (int i = 0; i < 4; ++i) {
        *(float4*)(&sX[0][(srow + 16 * i) * 68 + sk4 * 4]) = rx[i];
        *(float4*)(&sW[0][(srow + 16 * i) * 68 + sk4 * 4]) = rw[i];
    }
    __syncthreads();

    int cur = 0;
    for (int kc = 0; kc < 16; ++kc) {
        // prefetch next chunk into registers (in flight during compute)
        if (kc < 15) {
            int kb = k0 + (kc + 1) * 64;
            #pragma unroll
            for (int i = 0; i < 4; ++i) {
                int row = srow + 16 * i;
                rx[i] = *(const float4*)(x + (size_t)(rowBase + row) * 2048 + kb + sk4 * 4);
                rw[i] = *(const float4*)(proj_w + (size_t)row * 2048 + kb + sk4 * 4);
            }
        }
        // compute on buffer `cur`
        #pragma unroll
        for (int k4 = 0; k4 < 16; ++k4) {
            float4 xa[4], wa[4];
            #pragma unroll
            for (int rr = 0; rr < 4; ++rr)
                xa[rr] = *(const float4*)(&sX[cur][(rg + 16 * rr) * 68 + k4 * 4]);  // broadcast
            #pragma unroll
            for (int cc = 0; cc < 4; ++cc)
                wa[cc] = *(const float4*)(&sW[cur][(cg + 16 * cc) * 68 + k4 * 4]);  // 2-way max
            #pragma unroll
            for (int rr = 0; rr < 4; ++rr)
                #pragma unroll
                for (int cc = 0; cc < 4; ++cc)
                    acc[rr][cc] += dot4(xa[rr], wa[cc]);
        }
        // write prefetched regs into the other buffer, single barrier
        if (kc < 15) {
            int nxt = cur ^ 1;
            #pragma unroll
            for (int i = 0; i < 4; ++i) {
                *(float4*)(&sX[nxt][(srow + 16 * i) * 68 + sk4 * 4]) = rx[i];
                *(float4*)(&sW[nxt][(srow + 16 * i) * 68 + sk4 * 4]) = rw[i];
            }
            __syncthreads();
            cur = nxt;
        }
    }

    const size_t hbase = (size_t)blockIdx.y * (16384 * 64);
    #pragma unroll
    for (int rr = 0; rr < 4; ++rr)
        #pragma unroll
        for (int cc = 0; cc < 4; ++cc)
            hpart[hbase + (size_t)(rowBase + rg + 16 * rr) * 64 + cg + 16 * cc] = acc[rr][cc];
}

// ---------------- routing: logits -> segment softmax -> weighted pool -------
// grid 1024 (16 rows each), 256 threads; thread owns 8 neurons.
__launch_bounds__(256)
__global__ void route_kernel(const float* __restrict__ hpart,
                             const float* __restrict__ proj_b,
                             const float* __restrict__ imp,
                             const float* __restrict__ emb,
                             const float* __restrict__ emb_rel_k,
                             const float* __restrict__ invn_g,
                             const float* __restrict__ bonus_g,
                             float* __restrict__ wout)
{
    __shared__ float sH[16 * 64];
    __shared__ float2 red[8][8];    // (max, sum) per row per 32-lane half

    const int tid = threadIdx.x;
    const int rowBase = blockIdx.x * 16;
    const int b = rowBase >> 11;    // 2048 rows per batch

    // load h tile = hpart[0] + hpart[1] + bias
    {
        int row = tid >> 4, e0 = (tid & 15) * 4;
        size_t g = (size_t)(rowBase + row) * 64 + e0;
        float4 a = *(const float4*)(hpart + g);
        float4 c = *(const float4*)(hpart + (size_t)16384 * 64 + g);
        float4 bb = *(const float4*)(proj_b + e0);
        float4 r;
        r.x = a.x + c.x + bb.x; r.y = a.y + c.y + bb.y;
        r.z = a.z + c.z + bb.z; r.w = a.w + c.w + bb.w;
        *(float4*)(&sH[row * 64 + e0]) = r;
    }

    const int n0 = tid * 8;
    const float* ebase;
    if (n0 < 1280)      ebase = emb + (size_t)n0 * 64;
    else if (n0 < 1792) ebase = emb_rel_k + (size_t)(n0 - 1280) * 64;
    else                ebase = emb + (size_t)(n0 - 512) * 64;

    float invn[8], bon[8];
    #pragma unroll
    for (int j = 0; j < 8; ++j) { invn[j] = invn_g[n0 + j]; bon[j] = bonus_g[n0 + j]; }

    // segment -> which 32-lane halves to combine
    int h0, h1;
    if (tid < 64)       { h0 = 0; h1 = 1;  }   // qk  (n 0..511)
    else if (tid < 96)  { h0 = 2; h1 = -1; }   // fv  (512..767)
    else if (tid < 160) { h0 = 3; h1 = 4;  }   // q   (768..1279)
    else if (tid < 224) { h0 = 5; h1 = 6;  }   // k   (1280..1791)
    else                { h0 = 7; h1 = -1; }   // val (1792..2047)
    const int myhalf = tid >> 5;
    const int lane32 = tid & 31;

    __syncthreads();

    float accw[8];
    #pragma unroll
    for (int j = 0; j < 8; ++j) accw[j] = 0.f;

    for (int sb = 0; sb < 2; ++sb) {
        float l[8][8];
        #pragma unroll
        for (int r = 0; r < 8; ++r)
            #pragma unroll
            for (int j = 0; j < 8; ++j) l[r][j] = 0.f;

        #pragma unroll
        for (int k4 = 0; k4 < 16; ++k4) {
            float4 e4[8];
            #pragma unroll
            for (int j = 0; j < 8; ++j)
                e4[j] = *(const float4*)(ebase + j * 64 + k4 * 4);
            #pragma unroll
            for (int r = 0; r < 8; ++r) {
                float4 hx = *(const float4*)(&sH[(sb * 8 + r) * 64 + k4 * 4]);  // broadcast
                #pragma unroll
                for (int j = 0; j < 8; ++j)
                    l[r][j] += dot4(hx, e4[j]);
            }
        }

        // per-row: half-wave (m, s), then cross-half combine via (m,s) algebra
        float M[8];
        #pragma unroll
        for (int r = 0; r < 8; ++r) {
            float m = -INFINITY;
            #pragma unroll
            for (int j = 0; j < 8; ++j) {
                l[r][j] = fmaf(l[r][j], invn[j], bon[j]);
                m = fmaxf(m, l[r][j]);
            }
            #pragma unroll
            for (int d = 1; d <= 16; d <<= 1)
                m = fmaxf(m, __shfl_xor(m, d));
            M[r] = m;
        }
        float S[8];
        #pragma unroll
        for (int r = 0; r < 8; ++r) {
            float s = 0.f;
            #pragma unroll
            for (int j = 0; j < 8; ++j) {
                float t = __expf(l[r][j] - M[r]);
                l[r][j] = t;
                s += t;
            }
            #pragma unroll
            for (int d = 1; d <= 16; d <<= 1)
                s += __shfl_xor(s, d);
            S[r] = s;
        }
        if (lane32 == 0) {
            #pragma unroll
            for (int r = 0; r < 8; ++r) red[r][myhalf] = make_float2(M[r], S[r]);
        }
        __syncthreads();
        #pragma unroll
        for (int r = 0; r < 8; ++r) {
            float2 p0 = red[r][h0];
            float m = p0.x, z = p0.y;
            if (h1 >= 0) {
                float2 p1 = red[r][h1];
                float mm = fmaxf(m, p1.x);
                z = p0.y * __expf(p0.x - mm) + p1.y * __expf(p1.x - mm);
                m = mm;
            }
            int row = rowBase + sb * 8 + r;
            float coef = imp[row] / z * __expf(M[r] - m);
            #pragma unroll
            for (int j = 0; j < 8; ++j)
                accw[j] = fmaf(coef, l[r][j], accw[j]);
        }
        __syncthreads();
    }

    #pragma unroll
    for (int j = 0; j < 8; ++j)
        atomicAdd(&wout[b * 2048 + n0 + j], accw[j]);
}

// ---------------- top-k + softmax + sorted indices, one wave per (b,route) --
__global__ void topk_kernel(const float* __restrict__ w, float* __restrict__ out)
{
    const int lane = threadIdx.x;
    const int blk = blockIdx.x;          // 0..39
    const int b = blk / 5;
    const int route = blk % 5;

    const int segoff[5] = {0, 512, 768, 1280, 1792};
    const int seglen[5] = {512, 256, 512, 512, 256};
    const int kk[5]     = {64, 32, 64, 64, 32};
    const int soff[5]   = {0, 64, 96, 160, 224};
    const int ibase[5]  = {2048, 2560, 2816, 3328, 3840};

    const int L = seglen[route];
    const int K = kk[route];
    const int nv = L >> 6;               // 4 or 8 values per lane

    float v[8];
    #pragma unroll
    for (int i = 0; i < 8; ++i) {
        v[i] = -INFINITY;
        if (i < nv) v[i] = w[b * 2048 + segoff[route] + lane + 64 * i];
    }

    float selv = 0.f; int seli = 0;
    for (int it = 0; it < K; ++it) {
        float bv = -INFINITY; int bi = 0x7fffffff;
        #pragma unroll
        for (int i = 0; i < 8; ++i) {
            int li = lane + 64 * i;
            if (v[i] > bv || (v[i] == bv && li < bi)) { bv = v[i]; bi = li; }
        }
        for (int d = 1; d < 64; d <<= 1) {
            float ov = __shfl_xor(bv, d);
            int   oi = __shfl_xor(bi, d);
            if (ov > bv || (ov == bv && oi < bi)) { bv = ov; bi = oi; }
        }
        if (lane == it) { selv = bv; seli = bi; }
        #pragma unroll
        for (int i = 0; i < 8; ++i)
            if ((bi >> 6) == i && (bi & 63) == lane) v[i] = -INFINITY;
    }

    float m = __shfl(selv, 0);
    float e = (lane < K) ? __expf(selv - m) : 0.f;
    float s = e;
    for (int d = 1; d < 64; d <<= 1) s += __shfl_xor(s, d);
    if (lane < K) out[b * 256 + soff[route] + lane] = e / s;

    int rank = 0;
    for (int j = 0; j < K; ++j) {
        int oj = __shfl(seli, j);
        if (oj < seli) rank++;
    }
    if (lane < K) out[ibase[route] + b * K + rank] = (float)seli;
}

extern "C" void kernel_launch(void* const* d_in, const int* in_sizes, int n_in,
                              void* d_out, int out_size, void* d_ws, size_t ws_size,
                              hipStream_t stream)
{
    const float* x        = (const float*)d_in[0];
    const float* imp      = (const float*)d_in[1];
    const float* proj_w   = (const float*)d_in[2];
    const float* proj_b   = (const float*)d_in[3];
    const float* emb      = (const float*)d_in[4];
    const float* emb_rel  = (const float*)d_in[5];
    const float* ema_qk   = (const float*)d_in[6];
    const float* ema_v    = (const float*)d_in[7];
    const float* ema_rel  = (const float*)d_in[8];
    const float* ema_val  = (const float*)d_in[9];
    float* out = (float*)d_out;

    float* invn  = (float*)d_ws;             // 2048 f32
    float* bonus = invn + 2048;              // 2048 f32
    float* wacc  = bonus + 2048;             // 16384 f32
    float* hpart = wacc + 16384;             // 2 * 16384*64 f32 = 8 MB

    hipMemsetAsync(wacc, 0, 16384 * sizeof(float), stream);
    prep_kernel<<<32, 64, 0, stream>>>(emb, emb_rel, ema_qk, ema_v, ema_rel, ema_val, invn, bonus);
    proj_kernel<<<dim3(256, 2), 256, 0, stream>>>(x, proj_w, hpart);
    route_kernel<<<1024, 256, 0, stream>>>(hpart, proj_b, imp, emb, emb_rel, invn, bonus, wacc);
    topk_kernel<<<40, 64, 0, stream>>>(wacc, out);
}

// Round 3
// 414.595 us; speedup vs baseline: 1.7295x; 1.7295x over previous
//
#include <hip/hip_runtime.h>
#include <cmath>

// ---------------- prep: inv-norms + excitability bonus per global neuron ----
// global neuron order: [qk 0..511][fv 512..767][q 768..1279][k(rel) 1280..1791][val 1792..2047]
__global__ void prep_kernel(const float* __restrict__ emb,
                            const float* __restrict__ emb_rel_k,
                            const float* __restrict__ ema_qk,
                            const float* __restrict__ ema_v,
                            const float* __restrict__ ema_rel,
                            const float* __restrict__ ema_val,
                            float* __restrict__ invn,
                            float* __restrict__ bonus)
{
    int n = blockIdx.x * 64 + threadIdx.x;   // grid 32 x 64 -> 2048
    const float* row;
    float ema;
    if (n < 512)       { row = emb + (size_t)n * 64;                ema = ema_qk[n]; }
    else if (n < 768)  { row = emb + (size_t)n * 64;                ema = ema_v[n - 512]; }
    else if (n < 1280) { row = emb + (size_t)n * 64;                ema = ema_rel[n - 768]; }
    else if (n < 1792) { row = emb_rel_k + (size_t)(n - 1280) * 64; ema = ema_rel[n - 1280]; }
    else               { row = emb + (size_t)(n - 512) * 64;        ema = ema_val[n - 1792]; }
    float s = 0.f;
    #pragma unroll
    for (int k = 0; k < 64; k += 4) {
        float4 v = *(const float4*)(row + k);
        s += v.x*v.x + v.y*v.y + v.z*v.z + v.w*v.w;
    }
    invn[n] = 1.0f / sqrtf(s);
    float ex = 1.0f - ema * (1.0f / 1.5f);   // TAU = 1.5
    ex = fminf(fmaxf(ex, 0.f), 1.f);
    bonus[n] = ex * 1.0f;                    // EXC_W = 1.0
}

// ---------------- pack W: wtp[k4][e] = proj_w[e][4k..4k+3]  (float4/lane) ---
__global__ void wtpack_kernel(const float* __restrict__ proj_w, float* __restrict__ wtp)
{
    int idx = blockIdx.x * 256 + threadIdx.x;    // 32768 = 512 k4 x 64 e
    int e = idx & 63;
    int k4 = idx >> 6;
    float4 v = *(const float4*)(proj_w + (size_t)e * 2048 + k4 * 4);
    *(float4*)(wtp + (size_t)k4 * 256 + e * 4) = v;   // coalesced write
}

// ---------------- transpose emb (global order) into embT[64][2048] ----------
__global__ void embt_kernel(const float* __restrict__ emb,
                            const float* __restrict__ emb_rel_k,
                            float* __restrict__ embT)
{
    __shared__ float t[64 * 65];
    int tid = threadIdx.x;
    int n0 = blockIdx.x * 64;                    // 32 blocks
    const float* src;
    if (n0 < 1280)      src = emb + (size_t)n0 * 64;
    else if (n0 < 1792) src = emb_rel_k + (size_t)(n0 - 1280) * 64;
    else                src = emb + (size_t)(n0 - 512) * 64;
    #pragma unroll
    for (int i = 0; i < 16; ++i) {
        int idx = tid + 256 * i;                 // 0..4095
        int r = idx >> 6, c = idx & 63;          // r = local n, c = k
        t[c * 65 + r] = src[(size_t)r * 64 + c]; // coalesced read
    }
    __syncthreads();
    #pragma unroll
    for (int i = 0; i < 16; ++i) {
        int idx = tid + 256 * i;
        int k = idx >> 6, c = idx & 63;
        embT[(size_t)k * 2048 + n0 + c] = t[k * 65 + c];  // coalesced write
    }
}

// ---------------- proj GEMM: hpart[ks] = x[:, ks*512+:512] @ W^T ------------
// No LDS, no barriers. Wave owns 16 rows x 64 cols (lane = col).
__launch_bounds__(256, 4)
__global__ void proj_kernel(const float* __restrict__ x,
                            const float* __restrict__ wtp,
                            float* __restrict__ hpart)
{
    const int tid = threadIdx.x;
    const int wave = tid >> 6, lane = tid & 63;
    const int row0 = blockIdx.x * 64 + wave * 16;
    const int k4beg = blockIdx.y * 128;          // 128 k4-steps = 512 K
    const float* xb = x + (size_t)row0 * 2048;

    float acc[16];
    #pragma unroll
    for (int r = 0; r < 16; ++r) acc[r] = 0.f;

    for (int k4 = k4beg; k4 < k4beg + 128; ++k4) {
        float4 wt = *(const float4*)(wtp + (size_t)k4 * 256 + lane * 4);  // coalesced, L2
        #pragma unroll
        for (int r = 0; r < 16; ++r) {
            float4 xv = *(const float4*)(xb + (size_t)r * 2048 + k4 * 4); // wave-broadcast
            acc[r] = fmaf(xv.x, wt.x, fmaf(xv.y, wt.y,
                     fmaf(xv.z, wt.z, fmaf(xv.w, wt.w, acc[r]))));
        }
    }
    float* hp = hpart + (size_t)blockIdx.y * (16384 * 64);
    #pragma unroll
    for (int r = 0; r < 16; ++r)
        hp[(size_t)(row0 + r) * 64 + lane] = acc[r];     // 256B coalesced per row
}

// ---------------- hsum: h = sum of 4 K-partials + bias ----------------------
__global__ void hsum_kernel(const float* __restrict__ hpart,
                            const float* __restrict__ proj_b,
                            float* __restrict__ h)
{
    int idx = blockIdx.x * 256 + threadIdx.x;    // 262144 float4
    int c4 = (idx & 15) * 4;
    const size_t o = (size_t)idx * 4;
    const size_t sl = 16384 * 64;
    float4 a = *(const float4*)(hpart + o);
    float4 b1 = *(const float4*)(hpart + sl + o);
    float4 c = *(const float4*)(hpart + 2 * sl + o);
    float4 d = *(const float4*)(hpart + 3 * sl + o);
    float4 bb = *(const float4*)(proj_b + c4);
    float4 r;
    r.x = a.x + b1.x + c.x + d.x + bb.x;
    r.y = a.y + b1.y + c.y + d.y + bb.y;
    r.z = a.z + b1.z + c.z + d.z + bb.z;
    r.w = a.w + b1.w + c.w + d.w + bb.w;
    *(float4*)(h + o) = r;
}

// ---------------- routing: logits -> segment softmax -> weighted pool -------
// 512 threads, 16 rows/block, 4 neurons/thread. Segments are whole waves:
// waves 0,1=qk; 2=fv; 3,4=q; 5,6=k; 7=val.
__launch_bounds__(512, 4)
__global__ void route_kernel(const float* __restrict__ h,
                             const float* __restrict__ imp,
                             const float* __restrict__ embT,
                             const float* __restrict__ invn_g,
                             const float* __restrict__ bonus_g,
                             float* __restrict__ wout)
{
    __shared__ float2 red[16][8];   // (max, sum) per row per wave

    const int tid = threadIdx.x;
    const int wave = tid >> 6, lane = tid & 63;
    const int rowBase = blockIdx.x * 16;
    const int b = rowBase >> 11;
    const int n0 = tid * 4;
    const float* hb = h + (size_t)rowBase * 64;

    float l[16][4];
    #pragma unroll
    for (int r = 0; r < 16; ++r)
        #pragma unroll
        for (int j = 0; j < 4; ++j) l[r][j] = 0.f;

    for (int k4 = 0; k4 < 16; ++k4) {
        const float* eb = embT + (size_t)k4 * 4 * 2048 + n0;
        float4 et0 = *(const float4*)(eb);              // coalesced (2KB/wave)
        float4 et1 = *(const float4*)(eb + 2048);
        float4 et2 = *(const float4*)(eb + 4096);
        float4 et3 = *(const float4*)(eb + 6144);
        #pragma unroll
        for (int r = 0; r < 16; ++r) {
            float4 h4 = *(const float4*)(hb + r * 64 + k4 * 4);   // wave-broadcast, L1
            l[r][0] = fmaf(h4.x, et0.x, fmaf(h4.y, et1.x, fmaf(h4.z, et2.x, fmaf(h4.w, et3.x, l[r][0]))));
            l[r][1] = fmaf(h4.x, et0.y, fmaf(h4.y, et1.y, fmaf(h4.z, et2.y, fmaf(h4.w, et3.y, l[r][1]))));
            l[r][2] = fmaf(h4.x, et0.z, fmaf(h4.y, et1.z, fmaf(h4.z, et2.z, fmaf(h4.w, et3.z, l[r][2]))));
            l[r][3] = fmaf(h4.x, et0.w, fmaf(h4.y, et1.w, fmaf(h4.z, et2.w, fmaf(h4.w, et3.w, l[r][3]))));
        }
    }

    const float4 invn4 = *(const float4*)(invn_g + n0);
    const float4 bon4  = *(const float4*)(bonus_g + n0);

    // per-row: finalize logits, wave-level (m,s), stash to LDS
    #pragma unroll
    for (int r = 0; r < 16; ++r) {
        l[r][0] = fmaf(l[r][0], invn4.x, bon4.x);
        l[r][1] = fmaf(l[r][1], invn4.y, bon4.y);
        l[r][2] = fmaf(l[r][2], invn4.z, bon4.z);
        l[r][3] = fmaf(l[r][3], invn4.w, bon4.w);
        float m = fmaxf(fmaxf(l[r][0], l[r][1]), fmaxf(l[r][2], l[r][3]));
        #pragma unroll
        for (int d = 1; d < 64; d <<= 1)
            m = fmaxf(m, __shfl_xor(m, d));
        float s;
        l[r][0] = __expf(l[r][0] - m);
        l[r][1] = __expf(l[r][1] - m);
        l[r][2] = __expf(l[r][2] - m);
        l[r][3] = __expf(l[r][3] - m);
        s = l[r][0] + l[r][1] + l[r][2] + l[r][3];
        #pragma unroll
        for (int d = 1; d < 64; d <<= 1)
            s += __shfl_xor(s, d);
        if (lane == 0) red[r][wave] = make_float2(m, s);
    }
    __syncthreads();

    // cross-wave segment combine + weighted pool
    const unsigned PTAB = 0xF5634F01u;            // partner nibble per wave
    int pn = (PTAB >> (wave * 4)) & 0xF;
    float accw[4] = {0.f, 0.f, 0.f, 0.f};
    #pragma unroll
    for (int r = 0; r < 16; ++r) {
        float2 p = red[r][wave];
        float m = p.x, Z = p.y;
        if (pn != 0xF) {
            float2 q = red[r][pn];
            float mm = fmaxf(m, q.x);
            Z = p.y * __expf(p.x - mm) + q.y * __expf(q.x - mm);
            m = mm;
        }
        float coef = imp[rowBase + r] / Z * __expf(p.x - m);
        accw[0] = fmaf(coef, l[r][0], accw[0]);
        accw[1] = fmaf(coef, l[r][1], accw[1]);
        accw[2] = fmaf(coef, l[r][2], accw[2]);
        accw[3] = fmaf(coef, l[r][3], accw[3]);
    }
    atomicAdd(&wout[b * 2048 + n0 + 0], accw[0]);
    atomicAdd(&wout[b * 2048 + n0 + 1], accw[1]);
    atomicAdd(&wout[b * 2048 + n0 + 2], accw[2]);
    atomicAdd(&wout[b * 2048 + n0 + 3], accw[3]);
}

// ---------------- top-k + softmax + sorted indices, one wave per (b,route) --
__global__ void topk_kernel(const float* __restrict__ w, float* __restrict__ out)
{
    const int lane = threadIdx.x;
    const int blk = blockIdx.x;          // 0..39
    const int b = blk / 5;
    const int route = blk % 5;

    const int segoff[5] = {0, 512, 768, 1280, 1792};
    const int seglen[5] = {512, 256, 512, 512, 256};
    const int kk[5]     = {64, 32, 64, 64, 32};
    const int soff[5]   = {0, 64, 96, 160, 224};
    const int ibase[5]  = {2048, 2560, 2816, 3328, 3840};

    const int L = seglen[route];
    const int K = kk[route];
    const int nv = L >> 6;               // 4 or 8 values per lane

    float v[8];
    #pragma unroll
    for (int i = 0; i < 8; ++i) {
        v[i] = -INFINITY;
        if (i < nv) v[i] = w[b * 2048 + segoff[route] + lane + 64 * i];
    }

    float selv = 0.f; int seli = 0;
    for (int it = 0; it < K; ++it) {
        float bv = -INFINITY; int bi = 0x7fffffff;
        #pragma unroll
        for (int i = 0; i < 8; ++i) {
            int li = lane + 64 * i;
            if (v[i] > bv || (v[i] == bv && li < bi)) { bv = v[i]; bi = li; }
        }
        for (int d = 1; d < 64; d <<= 1) {
            float ov = __shfl_xor(bv, d);
            int   oi = __shfl_xor(bi, d);
            if (ov > bv || (ov == bv && oi < bi)) { bv = ov; bi = oi; }
        }
        if (lane == it) { selv = bv; seli = bi; }
        #pragma unroll
        for (int i = 0; i < 8; ++i)
            if ((bi >> 6) == i && (bi & 63) == lane) v[i] = -INFINITY;
    }

    float m = __shfl(selv, 0);
    float e = (lane < K) ? __expf(selv - m) : 0.f;
    float s = e;
    for (int d = 1; d < 64; d <<= 1) s += __shfl_xor(s, d);
    if (lane < K) out[b * 256 + soff[route] + lane] = e / s;

    int rank = 0;
    for (int j = 0; j < K; ++j) {
        int oj = __shfl(seli, j);
        if (oj < seli) rank++;
    }
    if (lane < K) out[ibase[route] + b * K + rank] = (float)seli;
}

extern "C" void kernel_launch(void* const* d_in, const int* in_sizes, int n_in,
                              void* d_out, int out_size, void* d_ws, size_t ws_size,
                              hipStream_t stream)
{
    const float* x        = (const float*)d_in[0];
    const float* imp      = (const float*)d_in[1];
    const float* proj_w   = (const float*)d_in[2];
    const float* proj_b   = (const float*)d_in[3];
    const float* emb      = (const float*)d_in[4];
    const float* emb_rel  = (const float*)d_in[5];
    const float* ema_qk   = (const float*)d_in[6];
    const float* ema_v    = (const float*)d_in[7];
    const float* ema_rel  = (const float*)d_in[8];
    const float* ema_val  = (const float*)d_in[9];
    float* out = (float*)d_out;

    float* invn  = (float*)d_ws;                 // 2048
    float* bonus = invn + 2048;                  // 2048
    float* wacc  = bonus + 2048;                 // 16384
    float* wtp   = wacc + 16384;                 // 131072 (512 KB)
    float* embT  = wtp + 131072;                 // 131072 (512 KB)
    float* h     = embT + 131072;                // 1048576 (4 MB)
    float* hpart = h + 1048576;                  // 4 x 1048576 (16 MB)

    hipMemsetAsync(wacc, 0, 16384 * sizeof(float), stream);
    prep_kernel<<<32, 64, 0, stream>>>(emb, emb_rel, ema_qk, ema_v, ema_rel, ema_val, invn, bonus);
    wtpack_kernel<<<128, 256, 0, stream>>>(proj_w, wtp);
    embt_kernel<<<32, 256, 0, stream>>>(emb, emb_rel, embT);
    proj_kernel<<<dim3(256, 4), 256, 0, stream>>>(x, wtp, hpart);
    hsum_kernel<<<1024, 256, 0, stream>>>(hpart, proj_b, h);
    route_kernel<<<1024, 512, 0, stream>>>(h, imp, embT, invn, bonus, wacc);
    topk_kernel<<<40, 64, 0, stream>>>(wacc, out);
}

// Round 4
// 238.929 us; speedup vs baseline: 3.0011x; 1.7352x over previous
//
#include <hip/hip_runtime.h>
#include <cmath>

typedef __attribute__((ext_vector_type(8))) short short8;
typedef __attribute__((ext_vector_type(4))) float f32x4;

static __device__ __forceinline__ unsigned short f2bf(float f) {
    unsigned u = __float_as_uint(f);
    unsigned r = (u + 0x7fffu + ((u >> 16) & 1u)) >> 16;
    return (unsigned short)r;
}
static __device__ __forceinline__ float bf2f(unsigned short h) {
    return __uint_as_float(((unsigned)h) << 16);
}

// ---------------- prep: inv-norms + excitability bonus per global neuron ----
// global neuron order: [qk 0..511][fv 512..767][q 768..1279][k(rel) 1280..1791][val 1792..2047]
__global__ void prep_kernel(const float* __restrict__ emb,
                            const float* __restrict__ emb_rel_k,
                            const float* __restrict__ ema_qk,
                            const float* __restrict__ ema_v,
                            const float* __restrict__ ema_rel,
                            const float* __restrict__ ema_val,
                            float* __restrict__ invn,
                            float* __restrict__ bonus)
{
    int n = blockIdx.x * 64 + threadIdx.x;   // grid 32 x 64 -> 2048
    const float* row;
    float ema;
    if (n < 512)       { row = emb + (size_t)n * 64;                ema = ema_qk[n]; }
    else if (n < 768)  { row = emb + (size_t)n * 64;                ema = ema_v[n - 512]; }
    else if (n < 1280) { row = emb + (size_t)n * 64;                ema = ema_rel[n - 768]; }
    else if (n < 1792) { row = emb_rel_k + (size_t)(n - 1280) * 64; ema = ema_rel[n - 1280]; }
    else               { row = emb + (size_t)(n - 512) * 64;        ema = ema_val[n - 1792]; }
    float s = 0.f;
    #pragma unroll
    for (int k = 0; k < 64; k += 4) {
        float4 v = *(const float4*)(row + k);
        s += v.x*v.x + v.y*v.y + v.z*v.z + v.w*v.w;
    }
    invn[n] = 1.0f / sqrtf(s);
    float ex = 1.0f - ema * (1.0f / 1.5f);   // TAU = 1.5
    ex = fminf(fmaxf(ex, 0.f), 1.f);
    bonus[n] = ex * 1.0f;                    // EXC_W = 1.0
}

// ---------------- pack W into 3 bf16 split planes, MFMA B-fragment order ----
// plane s (131072 u16): [ksg 0..63][t 0..3][lane 0..63][j 0..7]
// B[k][col] with col = 16t + (lane&15), k = ksg*32 + (lane>>4)*8 + j = W[col][k]
__global__ void wtpack3_kernel(const float* __restrict__ proj_w, unsigned short* __restrict__ wp)
{
    int idx = blockIdx.x * 256 + threadIdx.x;   // 16384 = 64 ksg x 4 t x 64 lane
    int l = idx & 63;
    int t = (idx >> 6) & 3;
    int ksg = idx >> 8;
    int col = t * 16 + (l & 15);
    int kb = ksg * 32 + (l >> 4) * 8;
    float4 w0 = *(const float4*)(proj_w + (size_t)col * 2048 + kb);
    float4 w1 = *(const float4*)(proj_w + (size_t)col * 2048 + kb + 4);
    float v[8] = {w0.x, w0.y, w0.z, w0.w, w1.x, w1.y, w1.z, w1.w};
    short8 s1, s2, s3;
    #pragma unroll
    for (int j = 0; j < 8; ++j) {
        unsigned short h1 = f2bf(v[j]); float f1 = bf2f(h1); float r1 = v[j] - f1;
        unsigned short h2 = f2bf(r1);   float f2 = bf2f(h2); float r2 = r1 - f2;
        unsigned short h3 = f2bf(r2);
        s1[j] = (short)h1; s2[j] = (short)h2; s3[j] = (short)h3;
    }
    size_t base = (size_t)ksg * 2048 + t * 512 + l * 8;
    *(short8*)(wp + base)            = s1;
    *(short8*)(wp + 131072 + base)   = s2;
    *(short8*)(wp + 2 * 131072 + base) = s3;
}

// ---------------- transpose emb (global order) into embT[64][2048] ----------
__global__ void embt_kernel(const float* __restrict__ emb,
                            const float* __restrict__ emb_rel_k,
                            float* __restrict__ embT)
{
    __shared__ float t[64 * 65];
    int tid = threadIdx.x;
    int n0 = blockIdx.x * 64;                    // 32 blocks
    const float* src;
    if (n0 < 1280)      src = emb + (size_t)n0 * 64;
    else if (n0 < 1792) src = emb_rel_k + (size_t)(n0 - 1280) * 64;
    else                src = emb + (size_t)(n0 - 512) * 64;
    #pragma unroll
    for (int i = 0; i < 16; ++i) {
        int idx = tid + 256 * i;                 // 0..4095
        int r = idx >> 6, c = idx & 63;          // r = local n, c = k
        t[c * 65 + r] = src[(size_t)r * 64 + c]; // coalesced read
    }
    __syncthreads();
    #pragma unroll
    for (int i = 0; i < 16; ++i) {
        int idx = tid + 256 * i;
        int k = idx >> 6, c = idx & 63;
        embT[(size_t)k * 2048 + n0 + c] = t[k * 65 + c];  // coalesced write
    }
}

// ---------------- proj GEMM via split-bf16 MFMA -----------------------------
// Block: 16 rows, 4 waves; wave w covers K [w*512,(w+1)*512) (16 k-steps of 32).
// In-block K-reduction via LDS, writes h (+bias) directly.
__launch_bounds__(256)
__global__ void proj_kernel(const float* __restrict__ x,
                            const unsigned short* __restrict__ wp,
                            const float* __restrict__ proj_b,
                            float* __restrict__ h)
{
    __shared__ float sAcc[4][1024];

    const int tid = threadIdx.x;
    const int wave = tid >> 6, lane = tid & 63;
    const int r_ = lane & 15, g_ = lane >> 4;
    const int row0 = blockIdx.x * 16;

    const float* xa = x + (size_t)(row0 + r_) * 2048 + wave * 512 + g_ * 8;

    f32x4 acc[4];
    #pragma unroll
    for (int t = 0; t < 4; ++t) acc[t] = (f32x4){0.f, 0.f, 0.f, 0.f};

    float4 a0 = *(const float4*)(xa);
    float4 a1 = *(const float4*)(xa + 4);

    for (int ks = 0; ks < 16; ++ks) {
        const int ksg = wave * 16 + ks;
        float4 n0_, n1_;
        if (ks < 15) {                                  // A prefetch (HBM)
            n0_ = *(const float4*)(xa + (ks + 1) * 32);
            n1_ = *(const float4*)(xa + (ks + 1) * 32 + 4);
        }
        // B fragments (L2-hot, coalesced 16B/lane)
        const unsigned short* wb = wp + (size_t)ksg * 2048 + lane * 8;
        short8 B1[4], B2[4], B3[4];
        #pragma unroll
        for (int t = 0; t < 4; ++t) {
            B1[t] = *(const short8*)(wb + t * 512);
            B2[t] = *(const short8*)(wb + 131072 + t * 512);
            B3[t] = *(const short8*)(wb + 2 * 131072 + t * 512);
        }
        // convert A to 3 bf16 splits
        float av[8] = {a0.x, a0.y, a0.z, a0.w, a1.x, a1.y, a1.z, a1.w};
        short8 A1, A2, A3;
        #pragma unroll
        for (int j = 0; j < 8; ++j) {
            float v = av[j];
            unsigned short h1 = f2bf(v); float f1 = bf2f(h1); float r1 = v - f1;
            unsigned short h2 = f2bf(r1); float f2 = bf2f(h2); float r2 = r1 - f2;
            unsigned short h3 = f2bf(r2);
            A1[j] = (short)h1; A2[j] = (short)h2; A3[j] = (short)h3;
        }
        // 6-product split accumulation (error ~2^-27 rel)
        #pragma unroll
        for (int t = 0; t < 4; ++t) {
            acc[t] = __builtin_amdgcn_mfma_f32_16x16x32_bf16(A1, B1[t], acc[t], 0, 0, 0);
            acc[t] = __builtin_amdgcn_mfma_f32_16x16x32_bf16(A1, B2[t], acc[t], 0, 0, 0);
            acc[t] = __builtin_amdgcn_mfma_f32_16x16x32_bf16(A2, B1[t], acc[t], 0, 0, 0);
            acc[t] = __builtin_amdgcn_mfma_f32_16x16x32_bf16(A2, B2[t], acc[t], 0, 0, 0);
            acc[t] = __builtin_amdgcn_mfma_f32_16x16x32_bf16(A1, B3[t], acc[t], 0, 0, 0);
            acc[t] = __builtin_amdgcn_mfma_f32_16x16x32_bf16(A3, B1[t], acc[t], 0, 0, 0);
        }
        a0 = n0_; a1 = n1_;
    }

    // D layout: row=(lane>>4)*4+r, col=t*16+(lane&15)
    #pragma unroll
    for (int t = 0; t < 4; ++t)
        #pragma unroll
        for (int r = 0; r < 4; ++r)
            sAcc[wave][(g_ * 4 + r) * 64 + t * 16 + r_] = acc[t][r];
    __syncthreads();

    // reduce 4 K-partials + bias, write h
    {
        int i0 = tid * 4;
        float4 a = *(const float4*)(&sAcc[0][i0]);
        float4 b = *(const float4*)(&sAcc[1][i0]);
        float4 c = *(const float4*)(&sAcc[2][i0]);
        float4 d = *(const float4*)(&sAcc[3][i0]);
        float4 bb = *(const float4*)(proj_b + (i0 & 63));
        float4 r;
        r.x = a.x + b.x + c.x + d.x + bb.x;
        r.y = a.y + b.y + c.y + d.y + bb.y;
        r.z = a.z + b.z + c.z + d.z + bb.z;
        r.w = a.w + b.w + c.w + d.w + bb.w;
        *(float4*)(h + (size_t)row0 * 64 + i0) = r;
    }
}

// ---------------- routing: logits -> segment softmax -> weighted pool -------
// 512 threads, 16 rows/block, 4 neurons/thread. Segments are whole waves:
// waves 0,1=qk; 2=fv; 3,4=q; 5,6=k; 7=val.
__launch_bounds__(512)
__global__ void route_kernel(const float* __restrict__ h,
                             const float* __restrict__ imp,
                             const float* __restrict__ embT,
                             const float* __restrict__ invn_g,
                             const float* __restrict__ bonus_g,
                             float* __restrict__ wout)
{
    __shared__ float sH[16 * 64];
    __shared__ float2 red[16][8];   // (max, sum) per row per wave

    const int tid = threadIdx.x;
    const int wave = tid >> 6, lane = tid & 63;
    const int rowBase = blockIdx.x * 16;
    const int b = rowBase >> 11;
    const int n0 = tid * 4;

    if (tid < 256)
        *(float4*)(&sH[tid * 4]) = *(const float4*)(h + (size_t)rowBase * 64 + tid * 4);
    __syncthreads();

    float l[16][4];
    #pragma unroll
    for (int r = 0; r < 16; ++r)
        #pragma unroll
        for (int j = 0; j < 4; ++j) l[r][j] = 0.f;

    float4 et0 = *(const float4*)(embT + n0);
    float4 et1 = *(const float4*)(embT + 2048 + n0);
    float4 et2 = *(const float4*)(embT + 4096 + n0);
    float4 et3 = *(const float4*)(embT + 6144 + n0);

    for (int k4 = 0; k4 < 16; ++k4) {
        float4 f0, f1, f2, f3;
        if (k4 < 15) {
            const float* eb = embT + (size_t)(k4 + 1) * 4 * 2048 + n0;
            f0 = *(const float4*)(eb);
            f1 = *(const float4*)(eb + 2048);
            f2 = *(const float4*)(eb + 4096);
            f3 = *(const float4*)(eb + 6144);
        }
        #pragma unroll
        for (int r = 0; r < 16; ++r) {
            float4 h4 = *(const float4*)(&sH[r * 64 + k4 * 4]);   // LDS broadcast
            l[r][0] = fmaf(h4.x, et0.x, fmaf(h4.y, et1.x, fmaf(h4.z, et2.x, fmaf(h4.w, et3.x, l[r][0]))));
            l[r][1] = fmaf(h4.x, et0.y, fmaf(h4.y, et1.y, fmaf(h4.z, et2.y, fmaf(h4.w, et3.y, l[r][1]))));
            l[r][2] = fmaf(h4.x, et0.z, fmaf(h4.y, et1.z, fmaf(h4.z, et2.z, fmaf(h4.w, et3.z, l[r][2]))));
            l[r][3] = fmaf(h4.x, et0.w, fmaf(h4.y, et1.w, fmaf(h4.z, et2.w, fmaf(h4.w, et3.w, l[r][3]))));
        }
        et0 = f0; et1 = f1; et2 = f2; et3 = f3;
    }

    const float4 invn4 = *(const float4*)(invn_g + n0);
    const float4 bon4  = *(const float4*)(bonus_g + n0);

    // per-row: finalize logits, wave-level (m,s), stash to LDS
    #pragma unroll
    for (int r = 0; r < 16; ++r) {
        l[r][0] = fmaf(l[r][0], invn4.x, bon4.x);
        l[r][1] = fmaf(l[r][1], invn4.y, bon4.y);
        l[r][2] = fmaf(l[r][2], invn4.z, bon4.z);
        l[r][3] = fmaf(l[r][3], invn4.w, bon4.w);
        float m = fmaxf(fmaxf(l[r][0], l[r][1]), fmaxf(l[r][2], l[r][3]));
        #pragma unroll
        for (int d = 1; d < 64; d <<= 1)
            m = fmaxf(m, __shfl_xor(m, d));
        float s;
        l[r][0] = __expf(l[r][0] - m);
        l[r][1] = __expf(l[r][1] - m);
        l[r][2] = __expf(l[r][2] - m);
        l[r][3] = __expf(l[r][3] - m);
        s = l[r][0] + l[r][1] + l[r][2] + l[r][3];
        #pragma unroll
        for (int d = 1; d < 64; d <<= 1)
            s += __shfl_xor(s, d);
        if (lane == 0) red[r][wave] = make_float2(m, s);
    }
    __syncthreads();

    // cross-wave segment combine + weighted pool
    const unsigned PTAB = 0xF5634F01u;            // partner nibble per wave
    int pn = (PTAB >> (wave * 4)) & 0xF;
    float accw[4] = {0.f, 0.f, 0.f, 0.f};
    #pragma unroll
    for (int r = 0; r < 16; ++r) {
        float2 p = red[r][wave];
        float m = p.x, Z = p.y;
        if (pn != 0xF) {
            float2 q = red[r][pn];
            float mm = fmaxf(m, q.x);
            Z = p.y * __expf(p.x - mm) + q.y * __expf(q.x - mm);
            m = mm;
        }
        float coef = imp[rowBase + r] / Z * __expf(p.x - m);
        accw[0] = fmaf(coef, l[r][0], accw[0]);
        accw[1] = fmaf(coef, l[r][1], accw[1]);
        accw[2] = fmaf(coef, l[r][2], accw[2]);
        accw[3] = fmaf(coef, l[r][3], accw[3]);
    }
    atomicAdd(&wout[b * 2048 + n0 + 0], accw[0]);
    atomicAdd(&wout[b * 2048 + n0 + 1], accw[1]);
    atomicAdd(&wout[b * 2048 + n0 + 2], accw[2]);
    atomicAdd(&wout[b * 2048 + n0 + 3], accw[3]);
}

// ---------------- top-k + softmax + sorted indices, one wave per (b,route) --
__global__ void topk_kernel(const float* __restrict__ w, float* __restrict__ out)
{
    const int lane = threadIdx.x;
    const int blk = blockIdx.x;          // 0..39
    const int b = blk / 5;
    const int route = blk % 5;

    const int segoff[5] = {0, 512, 768, 1280, 1792};
    const int seglen[5] = {512, 256, 512, 512, 256};
    const int kk[5]     = {64, 32, 64, 64, 32};
    const int soff[5]   = {0, 64, 96, 160, 224};
    const int ibase[5]  = {2048, 2560, 2816, 3328, 3840};

    const int L = seglen[route];
    const int K = kk[route];
    const int nv = L >> 6;               // 4 or 8 values per lane

    float v[8];
    #pragma unroll
    for (int i = 0; i < 8; ++i) {
        v[i] = -INFINITY;
        if (i < nv) v[i] = w[b * 2048 + segoff[route] + lane + 64 * i];
    }

    float selv = 0.f; int seli = 0;
    for (int it = 0; it < K; ++it) {
        float bv = -INFINITY; int bi = 0x7fffffff;
        #pragma unroll
        for (int i = 0; i < 8; ++i) {
            int li = lane + 64 * i;
            if (v[i] > bv || (v[i] == bv && li < bi)) { bv = v[i]; bi = li; }
        }
        for (int d = 1; d < 64; d <<= 1) {
            float ov = __shfl_xor(bv, d);
            int   oi = __shfl_xor(bi, d);
            if (ov > bv || (ov == bv && oi < bi)) { bv = ov; bi = oi; }
        }
        if (lane == it) { selv = bv; seli = bi; }
        #pragma unroll
        for (int i = 0; i < 8; ++i)
            if ((bi >> 6) == i && (bi & 63) == lane) v[i] = -INFINITY;
    }

    float m = __shfl(selv, 0);
    float e = (lane < K) ? __expf(selv - m) : 0.f;
    float s = e;
    for (int d = 1; d < 64; d <<= 1) s += __shfl_xor(s, d);
    if (lane < K) out[b * 256 + soff[route] + lane] = e / s;

    int rank = 0;
    for (int j = 0; j < K; ++j) {
        int oj = __shfl(seli, j);
        if (oj < seli) rank++;
    }
    if (lane < K) out[ibase[route] + b * K + rank] = (float)seli;
}

extern "C" void kernel_launch(void* const* d_in, const int* in_sizes, int n_in,
                              void* d_out, int out_size, void* d_ws, size_t ws_size,
                              hipStream_t stream)
{
    const float* x        = (const float*)d_in[0];
    const float* imp      = (const float*)d_in[1];
    const float* proj_w   = (const float*)d_in[2];
    const float* proj_b   = (const float*)d_in[3];
    const float* emb      = (const float*)d_in[4];
    const float* emb_rel  = (const float*)d_in[5];
    const float* ema_qk   = (const float*)d_in[6];
    const float* ema_v    = (const float*)d_in[7];
    const float* ema_rel  = (const float*)d_in[8];
    const float* ema_val  = (const float*)d_in[9];
    float* out = (float*)d_out;

    float* invn  = (float*)d_ws;                 // 2048
    float* bonus = invn + 2048;                  // 2048
    float* wacc  = bonus + 2048;                 // 16384
    float* embT  = wacc + 16384;                 // 131072 (512 KB)
    float* h     = embT + 131072;                // 1048576 (4 MB)
    unsigned short* wp = (unsigned short*)(h + 1048576);  // 3*131072 u16 (768 KB)

    hipMemsetAsync(wacc, 0, 16384 * sizeof(float), stream);
    prep_kernel<<<32, 64, 0, stream>>>(emb, emb_rel, ema_qk, ema_v, ema_rel, ema_val, invn, bonus);
    wtpack3_kernel<<<64, 256, 0, stream>>>(proj_w, wp);
    embt_kernel<<<32, 256, 0, stream>>>(emb, emb_rel, embT);
    proj_kernel<<<1024, 256, 0, stream>>>(x, wp, proj_b, h);
    route_kernel<<<1024, 512, 0, stream>>>(h, imp, embT, invn, bonus, wacc);
    topk_kernel<<<40, 64, 0, stream>>>(wacc, out);
}

// Round 5
// 145.027 us; speedup vs baseline: 4.9442x; 1.6475x over previous
//
#include <hip/hip_runtime.h>
#include <cmath>

typedef __attribute__((ext_vector_type(8))) short short8;
typedef __attribute__((ext_vector_type(4))) float f32x4;

static __device__ __forceinline__ unsigned short f2bf(float f) {
    unsigned u = __float_as_uint(f);
    unsigned r = (u + 0x7fffu + ((u >> 16) & 1u)) >> 16;
    return (unsigned short)r;
}
static __device__ __forceinline__ float bf2f(unsigned short h) {
    return __uint_as_float(((unsigned)h) << 16);
}
// fast 3-way split: levels 1-2 truncated, level 3 RNE; v = s1+s2+s3 + O(2^-25 |v|)
static __device__ __forceinline__ void split3(float v, short& o1, short& o2, short& o3) {
    unsigned u1 = __float_as_uint(v) & 0xffff0000u;
    float r1 = v - __uint_as_float(u1);
    unsigned u2 = __float_as_uint(r1) & 0xffff0000u;
    float r2 = r1 - __uint_as_float(u2);
    o1 = (short)(u1 >> 16);
    o2 = (short)(u2 >> 16);
    o3 = (short)f2bf(r2);
}

#define PH 1048576   // h plane elems (16384*64)
#define PB 131072    // emb/W plane elems (2048*64)

// ---------------- prep: inv-norms + excitability bonus per global neuron ----
// global order: [qk 0..511][fv 512..767][q 768..1279][k(rel) 1280..1791][val 1792..2047]
__global__ void prep_kernel(const float* __restrict__ emb,
                            const float* __restrict__ emb_rel_k,
                            const float* __restrict__ ema_qk,
                            const float* __restrict__ ema_v,
                            const float* __restrict__ ema_rel,
                            const float* __restrict__ ema_val,
                            float* __restrict__ invn,
                            float* __restrict__ bonus)
{
    int n = blockIdx.x * 64 + threadIdx.x;   // 32 x 64 -> 2048
    const float* row;
    float ema;
    if (n < 512)       { row = emb + (size_t)n * 64;                ema = ema_qk[n]; }
    else if (n < 768)  { row = emb + (size_t)n * 64;                ema = ema_v[n - 512]; }
    else if (n < 1280) { row = emb + (size_t)n * 64;                ema = ema_rel[n - 768]; }
    else if (n < 1792) { row = emb_rel_k + (size_t)(n - 1280) * 64; ema = ema_rel[n - 1280]; }
    else               { row = emb + (size_t)(n - 512) * 64;        ema = ema_val[n - 1792]; }
    float s = 0.f;
    #pragma unroll
    for (int k = 0; k < 64; k += 4) {
        float4 v = *(const float4*)(row + k);
        s += v.x*v.x + v.y*v.y + v.z*v.z + v.w*v.w;
    }
    invn[n] = 1.0f / sqrtf(s);
    float ex = 1.0f - ema * (1.0f / 1.5f);   // TAU = 1.5
    ex = fminf(fmaxf(ex, 0.f), 1.f);
    bonus[n] = ex * 1.0f;                    // EXC_W = 1.0
}

// ---------------- pack W into 3 bf16 split planes, MFMA B-fragment order ----
// plane: [ksg 0..63][t 0..3][lane 0..63][j 0..7]; col=16t+(l&15), k=ksg*32+(l>>4)*8+j
__global__ void wtpack3_kernel(const float* __restrict__ proj_w, unsigned short* __restrict__ wp)
{
    int idx = blockIdx.x * 256 + threadIdx.x;   // 16384
    int l = idx & 63;
    int t = (idx >> 6) & 3;
    int ksg = idx >> 8;
    int col = t * 16 + (l & 15);
    int kb = ksg * 32 + (l >> 4) * 8;
    float4 w0 = *(const float4*)(proj_w + (size_t)col * 2048 + kb);
    float4 w1 = *(const float4*)(proj_w + (size_t)col * 2048 + kb + 4);
    float v[8] = {w0.x, w0.y, w0.z, w0.w, w1.x, w1.y, w1.z, w1.w};
    short8 s1, s2, s3;
    #pragma unroll
    for (int j = 0; j < 8; ++j) {
        short a, b, c; split3(v[j], a, b, c);
        s1[j] = a; s2[j] = b; s3[j] = c;
    }
    size_t base = (size_t)ksg * 2048 + t * 512 + l * 8;
    *(short8*)(wp + base)          = s1;
    *(short8*)(wp + PB + base)     = s2;
    *(short8*)(wp + 2 * PB + base) = s3;
}

// ---------------- pack emb (global order) into 3 bf16 B-frag planes ---------
// plane: [nt 0..127][ks 0..1][lane][j]; neuron=nt*16+(l&15), k=ks*32+(l>>4)*8+j
__global__ void embpack_kernel(const float* __restrict__ emb,
                               const float* __restrict__ emb_rel_k,
                               unsigned short* __restrict__ bp)
{
    int idx = blockIdx.x * 256 + threadIdx.x;   // 16384
    int l = idx & 63;
    int ks = (idx >> 6) & 1;
    int nt = idx >> 7;
    int n = nt * 16 + (l & 15);
    const float* src;
    if (n < 1280)      src = emb + (size_t)n * 64;
    else if (n < 1792) src = emb_rel_k + (size_t)(n - 1280) * 64;
    else               src = emb + (size_t)(n - 512) * 64;
    int c0 = ks * 32 + (l >> 4) * 8;
    float4 w0 = *(const float4*)(src + c0);
    float4 w1 = *(const float4*)(src + c0 + 4);
    float v[8] = {w0.x, w0.y, w0.z, w0.w, w1.x, w1.y, w1.z, w1.w};
    short8 s1, s2, s3;
    #pragma unroll
    for (int j = 0; j < 8; ++j) {
        short a, b, c; split3(v[j], a, b, c);
        s1[j] = a; s2[j] = b; s3[j] = c;
    }
    size_t base = ((size_t)nt * 2 + ks) * 512 + l * 8;
    *(short8*)(bp + base)          = s1;
    *(short8*)(bp + PB + base)     = s2;
    *(short8*)(bp + 2 * PB + base) = s3;
}

#define MFMA16(a, b, c) __builtin_amdgcn_mfma_f32_16x16x32_bf16(a, b, c, 0, 0, 0)

// ---------------- proj GEMM via split-bf16 MFMA -----------------------------
// Block: 32 rows, 8 waves K-split (wave covers 256 K). LDS-reduce partials,
// add bias, emit h as 3 bf16 A-frag planes.
__launch_bounds__(512)
__global__ void proj_kernel(const float* __restrict__ x,
                            const unsigned short* __restrict__ wp,
                            const float* __restrict__ proj_b,
                            unsigned short* __restrict__ hs)
{
    __shared__ float sAcc[8][2048];   // 64 KB

    const int tid = threadIdx.x;
    const int wave = tid >> 6, lane = tid & 63;
    const int g_ = lane >> 4, r_ = lane & 15;
    const int row0 = blockIdx.x * 32;

    const float* xa0 = x + (size_t)(row0 + r_) * 2048 + wave * 256 + g_ * 8;
    const float* xa1 = xa0 + 16 * 2048;

    f32x4 acc[2][4];
    #pragma unroll
    for (int rt = 0; rt < 2; ++rt)
        #pragma unroll
        for (int t = 0; t < 4; ++t) acc[rt][t] = (f32x4){0.f, 0.f, 0.f, 0.f};

    float4 a00 = *(const float4*)(xa0);
    float4 a01 = *(const float4*)(xa0 + 4);
    float4 a10 = *(const float4*)(xa1);
    float4 a11 = *(const float4*)(xa1 + 4);

    for (int ks = 0; ks < 8; ++ks) {
        const int ksg = wave * 8 + ks;
        float4 n00, n01, n10, n11;
        if (ks < 7) {
            n00 = *(const float4*)(xa0 + (ks + 1) * 32);
            n01 = *(const float4*)(xa0 + (ks + 1) * 32 + 4);
            n10 = *(const float4*)(xa1 + (ks + 1) * 32);
            n11 = *(const float4*)(xa1 + (ks + 1) * 32 + 4);
        }
        const unsigned short* wb = wp + (size_t)ksg * 2048 + lane * 8;
        short8 B1[4], B2[4], B3[4];
        #pragma unroll
        for (int t = 0; t < 4; ++t) {
            B1[t] = *(const short8*)(wb + t * 512);
            B2[t] = *(const short8*)(wb + PB + t * 512);
            B3[t] = *(const short8*)(wb + 2 * PB + t * 512);
        }
        float av0[8] = {a00.x, a00.y, a00.z, a00.w, a01.x, a01.y, a01.z, a01.w};
        float av1[8] = {a10.x, a10.y, a10.z, a10.w, a11.x, a11.y, a11.z, a11.w};
        short8 A1[2], A2[2], A3[2];
        #pragma unroll
        for (int j = 0; j < 8; ++j) {
            short t1, t2, t3;
            split3(av0[j], t1, t2, t3); A1[0][j] = t1; A2[0][j] = t2; A3[0][j] = t3;
            split3(av1[j], t1, t2, t3); A1[1][j] = t1; A2[1][j] = t2; A3[1][j] = t3;
        }
        #pragma unroll
        for (int rt = 0; rt < 2; ++rt)
            #pragma unroll
            for (int t = 0; t < 4; ++t) {
                acc[rt][t] = MFMA16(A1[rt], B1[t], acc[rt][t]);
                acc[rt][t] = MFMA16(A1[rt], B2[t], acc[rt][t]);
                acc[rt][t] = MFMA16(A2[rt], B1[t], acc[rt][t]);
                acc[rt][t] = MFMA16(A2[rt], B2[t], acc[rt][t]);
                acc[rt][t] = MFMA16(A1[rt], B3[t], acc[rt][t]);
                acc[rt][t] = MFMA16(A3[rt], B1[t], acc[rt][t]);
            }
        a00 = n00; a01 = n01; a10 = n10; a11 = n11;
    }

    // D: row = g*4+rr (within 16-tile), col = t*16 + r_
    #pragma unroll
    for (int rt = 0; rt < 2; ++rt)
        #pragma unroll
        for (int t = 0; t < 4; ++t)
            #pragma unroll
            for (int rr = 0; rr < 4; ++rr)
                sAcc[wave][(rt * 16 + g_ * 4 + rr) * 64 + t * 16 + r_] = acc[rt][t][rr];
    __syncthreads();

    // reduce 8 K-partials + bias -> hbuf (reuse sAcc[0]); each thread owns 4 elems
    {
        int i0 = tid * 4;
        float4 s = *(const float4*)(&sAcc[0][i0]);
        #pragma unroll
        for (int w = 1; w < 8; ++w) {
            float4 p = *(const float4*)(&sAcc[w][i0]);
            s.x += p.x; s.y += p.y; s.z += p.z; s.w += p.w;
        }
        float4 bb = *(const float4*)(proj_b + (i0 & 63));
        s.x += bb.x; s.y += bb.y; s.z += bb.z; s.w += bb.w;
        *(float4*)(&sAcc[0][i0]) = s;
    }
    __syncthreads();

    // pack h tile into 3 A-frag planes (256 threads: 2 rt x 2 ks x 64 lanes)
    if (tid < 256) {
        int pl = tid & 63;
        int ks = (tid >> 6) & 1;
        int rt = tid >> 7;
        int row = rt * 16 + (pl & 15);
        int c0 = ks * 32 + (pl >> 4) * 8;
        const float* hb = &sAcc[0][row * 64 + c0];
        short8 s1, s2, s3;
        #pragma unroll
        for (int j = 0; j < 8; ++j) {
            short a, b, c; split3(hb[j], a, b, c);
            s1[j] = a; s2[j] = b; s3[j] = c;
        }
        size_t rg = (size_t)blockIdx.x * 2 + rt;
        size_t base = (rg * 2 + ks) * 512 + pl * 8;
        *(short8*)(hs + base)          = s1;
        *(short8*)(hs + PH + base)     = s2;
        *(short8*)(hs + 2 * PH + base) = s3;
    }
}

// ---------------- routing via MFMA: logits -> segment softmax -> pool -------
// Block: 32 rows, 8 waves; wave w owns neurons [w*256, w*256+256).
// Segments align to waves: 0-1=qk, 2=fv, 3-4=q, 5-6=k, 7=val.
__launch_bounds__(512)
__global__ void route_kernel(const unsigned short* __restrict__ hs,
                             const unsigned short* __restrict__ bp,
                             const float* __restrict__ imp,
                             const float* __restrict__ invn_g,
                             const float* __restrict__ bonus_g,
                             float* __restrict__ wout)
{
    __shared__ float2 red[32][8];

    const int tid = threadIdx.x;
    const int wave = tid >> 6, lane = tid & 63;
    const int g_ = lane >> 4, r_ = lane & 15;
    const int rowBase = blockIdx.x * 32;
    const int b = rowBase >> 11;
    const int n0 = wave * 256;

    // A-fragments for both 16-row tiles, both k-halves, 3 splits
    short8 A1[2][2], A2[2][2], A3[2][2];
    #pragma unroll
    for (int rt = 0; rt < 2; ++rt)
        #pragma unroll
        for (int ks = 0; ks < 2; ++ks) {
            size_t base = ((size_t)(blockIdx.x * 2 + rt) * 2 + ks) * 512 + lane * 8;
            A1[rt][ks] = *(const short8*)(hs + base);
            A2[rt][ks] = *(const short8*)(hs + PH + base);
            A3[rt][ks] = *(const short8*)(hs + 2 * PH + base);
        }

    f32x4 acc[2][16];
    #pragma unroll
    for (int rt = 0; rt < 2; ++rt)
        #pragma unroll
        for (int t = 0; t < 16; ++t) acc[rt][t] = (f32x4){0.f, 0.f, 0.f, 0.f};

    #pragma unroll
    for (int t = 0; t < 16; ++t) {
        const int nt = wave * 16 + t;
        #pragma unroll
        for (int ks = 0; ks < 2; ++ks) {
            size_t base = ((size_t)nt * 2 + ks) * 512 + lane * 8;
            short8 B1 = *(const short8*)(bp + base);
            short8 B2 = *(const short8*)(bp + PB + base);
            short8 B3 = *(const short8*)(bp + 2 * PB + base);
            #pragma unroll
            for (int rt = 0; rt < 2; ++rt) {
                acc[rt][t] = MFMA16(A1[rt][ks], B1, acc[rt][t]);
                acc[rt][t] = MFMA16(A1[rt][ks], B2, acc[rt][t]);
                acc[rt][t] = MFMA16(A2[rt][ks], B1, acc[rt][t]);
                acc[rt][t] = MFMA16(A2[rt][ks], B2, acc[rt][t]);
                acc[rt][t] = MFMA16(A1[rt][ks], B3, acc[rt][t]);
                acc[rt][t] = MFMA16(A3[rt][ks], B1, acc[rt][t]);
            }
        }
    }

    float inv_[16], bon_[16];
    #pragma unroll
    for (int t = 0; t < 16; ++t) {
        inv_[t] = invn_g[n0 + t * 16 + r_];
        bon_[t] = bonus_g[n0 + t * 16 + r_];
    }

    // pass 1: per (rt,r) row -> wave-local (max, expsum) -> LDS
    float m_[2][4], s_[2][4];
    #pragma unroll
    for (int rt = 0; rt < 2; ++rt)
        #pragma unroll
        for (int r = 0; r < 4; ++r) {
            float m = -INFINITY;
            float lv[16];
            #pragma unroll
            for (int t = 0; t < 16; ++t) {
                lv[t] = fmaf(acc[rt][t][r], inv_[t], bon_[t]);
                m = fmaxf(m, lv[t]);
            }
            #pragma unroll
            for (int d = 1; d <= 8; d <<= 1)
                m = fmaxf(m, __shfl_xor(m, d));
            float s = 0.f;
            #pragma unroll
            for (int t = 0; t < 16; ++t) s += __expf(lv[t] - m);
            #pragma unroll
            for (int d = 1; d <= 8; d <<= 1)
                s += __shfl_xor(s, d);
            m_[rt][r] = m; s_[rt][r] = s;
            if (r_ == 0) red[rt * 16 + g_ * 4 + r][wave] = make_float2(m, s);
        }
    __syncthreads();

    // pass 2: cross-wave combine, recompute P, weighted pool
    const unsigned PTAB = 0xF5634F01u;
    const int pn = (PTAB >> (wave * 4)) & 0xF;
    float accw[16];
    #pragma unroll
    for (int t = 0; t < 16; ++t) accw[t] = 0.f;

    #pragma unroll
    for (int rt = 0; rt < 2; ++rt)
        #pragma unroll
        for (int r = 0; r < 4; ++r) {
            const int row = rt * 16 + g_ * 4 + r;
            float m = m_[rt][r], s = s_[rt][r];
            float M = m, Z = s;
            if (pn != 0xF) {
                float2 q = red[row][pn];
                M = fmaxf(m, q.x);
                Z = s * __expf(m - M) + q.y * __expf(q.x - M);
            }
            float coef = imp[rowBase + row] / Z * __expf(m - M);
            #pragma unroll
            for (int t = 0; t < 16; ++t)
                accw[t] = fmaf(coef, __expf(fmaf(acc[rt][t][r], inv_[t], bon_[t]) - m), accw[t]);
        }

    // reduce the 4 g-groups (rows) per column, then write
    #pragma unroll
    for (int t = 0; t < 16; ++t) {
        accw[t] += __shfl_xor(accw[t], 16);
        accw[t] += __shfl_xor(accw[t], 32);
    }
    #pragma unroll
    for (int tt = 0; tt < 4; ++tt) {
        int t = g_ * 4 + tt;
        float v = (tt == 0) ? accw[g_ * 4] : (tt == 1) ? accw[g_ * 4 + 1]
                : (tt == 2) ? accw[g_ * 4 + 2] : accw[g_ * 4 + 3];
        atomicAdd(&wout[b * 2048 + n0 + t * 16 + r_], v);
    }
}

// ---------------- top-k + softmax + sorted indices, one wave per (b,route) --
__global__ void topk_kernel(const float* __restrict__ w, float* __restrict__ out)
{
    const int lane = threadIdx.x;
    const int blk = blockIdx.x;          // 0..39
    const int b = blk / 5;
    const int route = blk % 5;

    const int segoff[5] = {0, 512, 768, 1280, 1792};
    const int seglen[5] = {512, 256, 512, 512, 256};
    const int kk[5]     = {64, 32, 64, 64, 32};
    const int soff[5]   = {0, 64, 96, 160, 224};
    const int ibase[5]  = {2048, 2560, 2816, 3328, 3840};

    const int L = seglen[route];
    const int K = kk[route];
    const int nv = L >> 6;               // 4 or 8 values per lane

    float v[8];
    #pragma unroll
    for (int i = 0; i < 8; ++i) {
        v[i] = -INFINITY;
        if (i < nv) v[i] = w[b * 2048 + segoff[route] + lane + 64 * i];
    }

    float selv = 0.f; int seli = 0;
    for (int it = 0; it < K; ++it) {
        float bv = -INFINITY; int bi = 0x7fffffff;
        #pragma unroll
        for (int i = 0; i < 8; ++i) {
            int li = lane + 64 * i;
            if (v[i] > bv || (v[i] == bv && li < bi)) { bv = v[i]; bi = li; }
        }
        for (int d = 1; d < 64; d <<= 1) {
            float ov = __shfl_xor(bv, d);
            int   oi = __shfl_xor(bi, d);
            if (ov > bv || (ov == bv && oi < bi)) { bv = ov; bi = oi; }
        }
        if (lane == it) { selv = bv; seli = bi; }
        #pragma unroll
        for (int i = 0; i < 8; ++i)
            if ((bi >> 6) == i && (bi & 63) == lane) v[i] = -INFINITY;
    }

    float m = __shfl(selv, 0);
    float e = (lane < K) ? __expf(selv - m) : 0.f;
    float s = e;
    for (int d = 1; d < 64; d <<= 1) s += __shfl_xor(s, d);
    if (lane < K) out[b * 256 + soff[route] + lane] = e / s;

    int rank = 0;
    for (int j = 0; j < K; ++j) {
        int oj = __shfl(seli, j);
        if (oj < seli) rank++;
    }
    if (lane < K) out[ibase[route] + b * K + rank] = (float)seli;
}

extern "C" void kernel_launch(void* const* d_in, const int* in_sizes, int n_in,
                              void* d_out, int out_size, void* d_ws, size_t ws_size,
                              hipStream_t stream)
{
    const float* x        = (const float*)d_in[0];
    const float* imp      = (const float*)d_in[1];
    const float* proj_w   = (const float*)d_in[2];
    const float* proj_b   = (const float*)d_in[3];
    const float* emb      = (const float*)d_in[4];
    const float* emb_rel  = (const float*)d_in[5];
    const float* ema_qk   = (const float*)d_in[6];
    const float* ema_v    = (const float*)d_in[7];
    const float* ema_rel  = (const float*)d_in[8];
    const float* ema_val  = (const float*)d_in[9];
    float* out = (float*)d_out;

    float* invn  = (float*)d_ws;                       // 2048 f32
    float* bonus = invn + 2048;                        // 2048 f32
    float* wacc  = bonus + 2048;                       // 16384 f32
    unsigned short* wp = (unsigned short*)(wacc + 16384);  // 3*PB u16
    unsigned short* bp = wp + 3 * PB;                  // 3*PB u16
    unsigned short* hs = bp + 3 * PB;                  // 3*PH u16 (6 MB)

    hipMemsetAsync(wacc, 0, 16384 * sizeof(float), stream);
    prep_kernel<<<32, 64, 0, stream>>>(emb, emb_rel, ema_qk, ema_v, ema_rel, ema_val, invn, bonus);
    wtpack3_kernel<<<64, 256, 0, stream>>>(proj_w, wp);
    embpack_kernel<<<64, 256, 0, stream>>>(emb, emb_rel, bp);
    proj_kernel<<<512, 512, 0, stream>>>(x, wp, proj_b, hs);
    route_kernel<<<512, 512, 0, stream>>>(hs, bp, imp, invn, bonus, wacc);
    topk_kernel<<<40, 64, 0, stream>>>(wacc, out);
}

// Round 6
// 142.042 us; speedup vs baseline: 5.0481x; 1.0210x over previous
//
#include <hip/hip_runtime.h>
#include <cmath>

typedef __attribute__((ext_vector_type(8))) short short8;
typedef __attribute__((ext_vector_type(4))) float f32x4;

static __device__ __forceinline__ unsigned short f2bf(float f) {
    unsigned u = __float_as_uint(f);
    unsigned r = (u + 0x7fffu + ((u >> 16) & 1u)) >> 16;
    return (unsigned short)r;
}
static __device__ __forceinline__ float bf2f(unsigned short h) {
    return __uint_as_float(((unsigned)h) << 16);
}
// fast 3-way split: levels 1-2 truncated, level 3 RNE; v = s1+s2+s3 + O(2^-25 |v|)
static __device__ __forceinline__ void split3(float v, short& o1, short& o2, short& o3) {
    unsigned u1 = __float_as_uint(v) & 0xffff0000u;
    float r1 = v - __uint_as_float(u1);
    unsigned u2 = __float_as_uint(r1) & 0xffff0000u;
    float r2 = r1 - __uint_as_float(u2);
    o1 = (short)(u1 >> 16);
    o2 = (short)(u2 >> 16);
    o3 = (short)f2bf(r2);
}

#define PH 1048576   // h plane elems (16384*64)
#define PB 131072    // emb/W plane elems (2048*64)

// ---------------- prep: zero wacc + inv-norms + excitability bonus ----------
// global order: [qk 0..511][fv 512..767][q 768..1279][k(rel) 1280..1791][val 1792..2047]
__global__ void prep_kernel(const float* __restrict__ emb,
                            const float* __restrict__ emb_rel_k,
                            const float* __restrict__ ema_qk,
                            const float* __restrict__ ema_v,
                            const float* __restrict__ ema_rel,
                            const float* __restrict__ ema_val,
                            float* __restrict__ invn,
                            float* __restrict__ bonus,
                            float* __restrict__ wacc)
{
    int n = blockIdx.x * 64 + threadIdx.x;   // 32 x 64 -> 2048
    // zero the 16384-float atomic accumulator (8 floats/thread)
    {
        float4 z = {0.f, 0.f, 0.f, 0.f};
        *(float4*)(wacc + (size_t)n * 8)     = z;
        *(float4*)(wacc + (size_t)n * 8 + 4) = z;
    }
    const float* row;
    float ema;
    if (n < 512)       { row = emb + (size_t)n * 64;                ema = ema_qk[n]; }
    else if (n < 768)  { row = emb + (size_t)n * 64;                ema = ema_v[n - 512]; }
    else if (n < 1280) { row = emb + (size_t)n * 64;                ema = ema_rel[n - 768]; }
    else if (n < 1792) { row = emb_rel_k + (size_t)(n - 1280) * 64; ema = ema_rel[n - 1280]; }
    else               { row = emb + (size_t)(n - 512) * 64;        ema = ema_val[n - 1792]; }
    float s = 0.f;
    #pragma unroll
    for (int k = 0; k < 64; k += 4) {
        float4 v = *(const float4*)(row + k);
        s += v.x*v.x + v.y*v.y + v.z*v.z + v.w*v.w;
    }
    invn[n] = 1.0f / sqrtf(s);
    float ex = 1.0f - ema * (1.0f / 1.5f);   // TAU = 1.5
    ex = fminf(fmaxf(ex, 0.f), 1.f);
    bonus[n] = ex * 1.0f;                    // EXC_W = 1.0
}

// ---------------- pack W into 3 bf16 split planes, MFMA B-fragment order ----
// plane: [ksg 0..63][t 0..3][lane 0..63][j 0..7]; col=16t+(l&15), k=ksg*32+(l>>4)*8+j
__global__ void wtpack3_kernel(const float* __restrict__ proj_w, unsigned short* __restrict__ wp)
{
    int idx = blockIdx.x * 256 + threadIdx.x;   // 16384
    int l = idx & 63;
    int t = (idx >> 6) & 3;
    int ksg = idx >> 8;
    int col = t * 16 + (l & 15);
    int kb = ksg * 32 + (l >> 4) * 8;
    float4 w0 = *(const float4*)(proj_w + (size_t)col * 2048 + kb);
    float4 w1 = *(const float4*)(proj_w + (size_t)col * 2048 + kb + 4);
    float v[8] = {w0.x, w0.y, w0.z, w0.w, w1.x, w1.y, w1.z, w1.w};
    short8 s1, s2, s3;
    #pragma unroll
    for (int j = 0; j < 8; ++j) {
        short a, b, c; split3(v[j], a, b, c);
        s1[j] = a; s2[j] = b; s3[j] = c;
    }
    size_t base = (size_t)ksg * 2048 + t * 512 + l * 8;
    *(short8*)(wp + base)          = s1;
    *(short8*)(wp + PB + base)     = s2;
    *(short8*)(wp + 2 * PB + base) = s3;
}

// ---------------- pack emb (global order) into 3 bf16 B-frag planes ---------
// plane: [nt 0..127][ks 0..1][lane][j]; neuron=nt*16+(l&15), k=ks*32+(l>>4)*8+j
__global__ void embpack_kernel(const float* __restrict__ emb,
                               const float* __restrict__ emb_rel_k,
                               unsigned short* __restrict__ bp)
{
    int idx = blockIdx.x * 256 + threadIdx.x;   // 16384
    int l = idx & 63;
    int ks = (idx >> 6) & 1;
    int nt = idx >> 7;
    int n = nt * 16 + (l & 15);
    const float* src;
    if (n < 1280)      src = emb + (size_t)n * 64;
    else if (n < 1792) src = emb_rel_k + (size_t)(n - 1280) * 64;
    else               src = emb + (size_t)(n - 512) * 64;
    int c0 = ks * 32 + (l >> 4) * 8;
    float4 w0 = *(const float4*)(src + c0);
    float4 w1 = *(const float4*)(src + c0 + 4);
    float v[8] = {w0.x, w0.y, w0.z, w0.w, w1.x, w1.y, w1.z, w1.w};
    short8 s1, s2, s3;
    #pragma unroll
    for (int j = 0; j < 8; ++j) {
        short a, b, c; split3(v[j], a, b, c);
        s1[j] = a; s2[j] = b; s3[j] = c;
    }
    size_t base = ((size_t)nt * 2 + ks) * 512 + l * 8;
    *(short8*)(bp + base)          = s1;
    *(short8*)(bp + PB + base)     = s2;
    *(short8*)(bp + 2 * PB + base) = s3;
}

#define MFMA16(a, b, c) __builtin_amdgcn_mfma_f32_16x16x32_bf16(a, b, c, 0, 0, 0)

// ---------------- proj GEMM via split-bf16 MFMA -----------------------------
// Block: 32 rows, 8 waves K-split (wave covers 256 K). LDS-reduce partials,
// add bias, emit h as 3 bf16 A-frag planes.
__launch_bounds__(512)
__global__ void proj_kernel(const float* __restrict__ x,
                            const unsigned short* __restrict__ wp,
                            const float* __restrict__ proj_b,
                            unsigned short* __restrict__ hs)
{
    __shared__ float sAcc[8][2048];   // 64 KB

    const int tid = threadIdx.x;
    const int wave = tid >> 6, lane = tid & 63;
    const int g_ = lane >> 4, r_ = lane & 15;
    const int row0 = blockIdx.x * 32;

    const float* xa0 = x + (size_t)(row0 + r_) * 2048 + wave * 256 + g_ * 8;
    const float* xa1 = xa0 + 16 * 2048;

    f32x4 acc[2][4];
    #pragma unroll
    for (int rt = 0; rt < 2; ++rt)
        #pragma unroll
        for (int t = 0; t < 4; ++t) acc[rt][t] = (f32x4){0.f, 0.f, 0.f, 0.f};

    float4 a00 = *(const float4*)(xa0);
    float4 a01 = *(const float4*)(xa0 + 4);
    float4 a10 = *(const float4*)(xa1);
    float4 a11 = *(const float4*)(xa1 + 4);

    for (int ks = 0; ks < 8; ++ks) {
        const int ksg = wave * 8 + ks;
        float4 n00, n01, n10, n11;
        if (ks < 7) {
            n00 = *(const float4*)(xa0 + (ks + 1) * 32);
            n01 = *(const float4*)(xa0 + (ks + 1) * 32 + 4);
            n10 = *(const float4*)(xa1 + (ks + 1) * 32);
            n11 = *(const float4*)(xa1 + (ks + 1) * 32 + 4);
        }
        const unsigned short* wb = wp + (size_t)ksg * 2048 + lane * 8;
        short8 B1[4], B2[4], B3[4];
        #pragma unroll
        for (int t = 0; t < 4; ++t) {
            B1[t] = *(const short8*)(wb + t * 512);
            B2[t] = *(const short8*)(wb + PB + t * 512);
            B3[t] = *(const short8*)(wb + 2 * PB + t * 512);
        }
        float av0[8] = {a00.x, a00.y, a00.z, a00.w, a01.x, a01.y, a01.z, a01.w};
        float av1[8] = {a10.x, a10.y, a10.z, a10.w, a11.x, a11.y, a11.z, a11.w};
        short8 A1[2], A2[2], A3[2];
        #pragma unroll
        for (int j = 0; j < 8; ++j) {
            short t1, t2, t3;
            split3(av0[j], t1, t2, t3); A1[0][j] = t1; A2[0][j] = t2; A3[0][j] = t3;
            split3(av1[j], t1, t2, t3); A1[1][j] = t1; A2[1][j] = t2; A3[1][j] = t3;
        }
        #pragma unroll
        for (int rt = 0; rt < 2; ++rt)
            #pragma unroll
            for (int t = 0; t < 4; ++t) {
                acc[rt][t] = MFMA16(A1[rt], B1[t], acc[rt][t]);
                acc[rt][t] = MFMA16(A1[rt], B2[t], acc[rt][t]);
                acc[rt][t] = MFMA16(A2[rt], B1[t], acc[rt][t]);
                acc[rt][t] = MFMA16(A2[rt], B2[t], acc[rt][t]);
                acc[rt][t] = MFMA16(A1[rt], B3[t], acc[rt][t]);
                acc[rt][t] = MFMA16(A3[rt], B1[t], acc[rt][t]);
            }
        a00 = n00; a01 = n01; a10 = n10; a11 = n11;
    }

    // D: row = g*4+rr (within 16-tile), col = t*16 + r_
    #pragma unroll
    for (int rt = 0; rt < 2; ++rt)
        #pragma unroll
        for (int t = 0; t < 4; ++t)
            #pragma unroll
            for (int rr = 0; rr < 4; ++rr)
                sAcc[wave][(rt * 16 + g_ * 4 + rr) * 64 + t * 16 + r_] = acc[rt][t][rr];
    __syncthreads();

    // reduce 8 K-partials + bias -> hbuf (reuse sAcc[0]); each thread owns 4 elems
    {
        int i0 = tid * 4;
        float4 s = *(const float4*)(&sAcc[0][i0]);
        #pragma unroll
        for (int w = 1; w < 8; ++w) {
            float4 p = *(const float4*)(&sAcc[w][i0]);
            s.x += p.x; s.y += p.y; s.z += p.z; s.w += p.w;
        }
        float4 bb = *(const float4*)(proj_b + (i0 & 63));
        s.x += bb.x; s.y += bb.y; s.z += bb.z; s.w += bb.w;
        *(float4*)(&sAcc[0][i0]) = s;
    }
    __syncthreads();

    // pack h tile into 3 A-frag planes (256 threads: 2 rt x 2 ks x 64 lanes)
    if (tid < 256) {
        int pl = tid & 63;
        int ks = (tid >> 6) & 1;
        int rt = tid >> 7;
        int row = rt * 16 + (pl & 15);
        int c0 = ks * 32 + (pl >> 4) * 8;
        const float* hb = &sAcc[0][row * 64 + c0];
        short8 s1, s2, s3;
        #pragma unroll
        for (int j = 0; j < 8; ++j) {
            short a, b, c; split3(hb[j], a, b, c);
            s1[j] = a; s2[j] = b; s3[j] = c;
        }
        size_t rg = (size_t)blockIdx.x * 2 + rt;
        size_t base = (rg * 2 + ks) * 512 + pl * 8;
        *(short8*)(hs + base)          = s1;
        *(short8*)(hs + PH + base)     = s2;
        *(short8*)(hs + 2 * PH + base) = s3;
    }
}

// ---------------- routing via MFMA: logits -> segment softmax -> pool -------
// Block: 32 rows, 8 waves; wave w owns neurons [w*256, w*256+256).
// Segments align to waves: 0-1=qk, 2=fv, 3-4=q, 5-6=k, 7=val.
__launch_bounds__(512)
__global__ void route_kernel(const unsigned short* __restrict__ hs,
                             const unsigned short* __restrict__ bp,
                             const float* __restrict__ imp,
                             const float* __restrict__ invn_g,
                             const float* __restrict__ bonus_g,
                             float* __restrict__ wout)
{
    __shared__ float2 red[32][8];

    const int tid = threadIdx.x;
    const int wave = tid >> 6, lane = tid & 63;
    const int g_ = lane >> 4, r_ = lane & 15;
    const int rowBase = blockIdx.x * 32;
    const int b = rowBase >> 11;
    const int n0 = wave * 256;

    // A-fragments for both 16-row tiles, both k-halves, 3 splits
    short8 A1[2][2], A2[2][2], A3[2][2];
    #pragma unroll
    for (int rt = 0; rt < 2; ++rt)
        #pragma unroll
        for (int ks = 0; ks < 2; ++ks) {
            size_t base = ((size_t)(blockIdx.x * 2 + rt) * 2 + ks) * 512 + lane * 8;
            A1[rt][ks] = *(const short8*)(hs + base);
            A2[rt][ks] = *(const short8*)(hs + PH + base);
            A3[rt][ks] = *(const short8*)(hs + 2 * PH + base);
        }

    f32x4 acc[2][16];
    #pragma unroll
    for (int rt = 0; rt < 2; ++rt)
        #pragma unroll
        for (int t = 0; t < 16; ++t) acc[rt][t] = (f32x4){0.f, 0.f, 0.f, 0.f};

    #pragma unroll
    for (int t = 0; t < 16; ++t) {
        const int nt = wave * 16 + t;
        #pragma unroll
        for (int ks = 0; ks < 2; ++ks) {
            size_t base = ((size_t)nt * 2 + ks) * 512 + lane * 8;
            short8 B1 = *(const short8*)(bp + base);
            short8 B2 = *(const short8*)(bp + PB + base);
            short8 B3 = *(const short8*)(bp + 2 * PB + base);
            #pragma unroll
            for (int rt = 0; rt < 2; ++rt) {
                acc[rt][t] = MFMA16(A1[rt][ks], B1, acc[rt][t]);
                acc[rt][t] = MFMA16(A1[rt][ks], B2, acc[rt][t]);
                acc[rt][t] = MFMA16(A2[rt][ks], B1, acc[rt][t]);
                acc[rt][t] = MFMA16(A2[rt][ks], B2, acc[rt][t]);
                acc[rt][t] = MFMA16(A1[rt][ks], B3, acc[rt][t]);
                acc[rt][t] = MFMA16(A3[rt][ks], B1, acc[rt][t]);
            }
        }
    }

    float inv_[16], bon_[16];
    #pragma unroll
    for (int t = 0; t < 16; ++t) {
        inv_[t] = invn_g[n0 + t * 16 + r_];
        bon_[t] = bonus_g[n0 + t * 16 + r_];
    }

    // pass 1: per (rt,r) row -> wave-local (max, expsum) -> LDS
    float m_[2][4], s_[2][4];
    #pragma unroll
    for (int rt = 0; rt < 2; ++rt)
        #pragma unroll
        for (int r = 0; r < 4; ++r) {
            float m = -INFINITY;
            float lv[16];
            #pragma unroll
            for (int t = 0; t < 16; ++t) {
                lv[t] = fmaf(acc[rt][t][r], inv_[t], bon_[t]);
                m = fmaxf(m, lv[t]);
            }
            #pragma unroll
            for (int d = 1; d <= 8; d <<= 1)
                m = fmaxf(m, __shfl_xor(m, d));
            float s = 0.f;
            #pragma unroll
            for (int t = 0; t < 16; ++t) s += __expf(lv[t] - m);
            #pragma unroll
            for (int d = 1; d <= 8; d <<= 1)
                s += __shfl_xor(s, d);
            m_[rt][r] = m; s_[rt][r] = s;
            if (r_ == 0) red[rt * 16 + g_ * 4 + r][wave] = make_float2(m, s);
        }
    __syncthreads();

    // pass 2: cross-wave combine, recompute P, weighted pool
    const unsigned PTAB = 0xF5634F01u;
    const int pn = (PTAB >> (wave * 4)) & 0xF;
    float accw[16];
    #pragma unroll
    for (int t = 0; t < 16; ++t) accw[t] = 0.f;

    #pragma unroll
    for (int rt = 0; rt < 2; ++rt)
        #pragma unroll
        for (int r = 0; r < 4; ++r) {
            const int row = rt * 16 + g_ * 4 + r;
            float m = m_[rt][r], s = s_[rt][r];
            float M = m, Z = s;
            if (pn != 0xF) {
                float2 q = red[row][pn];
                M = fmaxf(m, q.x);
                Z = s * __expf(m - M) + q.y * __expf(q.x - M);
            }
            float coef = imp[rowBase + row] / Z * __expf(m - M);
            #pragma unroll
            for (int t = 0; t < 16; ++t)
                accw[t] = fmaf(coef, __expf(fmaf(acc[rt][t][r], inv_[t], bon_[t]) - m), accw[t]);
        }

    // reduce the 4 g-groups (rows) per column, then write
    #pragma unroll
    for (int t = 0; t < 16; ++t) {
        accw[t] += __shfl_xor(accw[t], 16);
        accw[t] += __shfl_xor(accw[t], 32);
    }
    #pragma unroll
    for (int tt = 0; tt < 4; ++tt) {
        int t = g_ * 4 + tt;
        float v = (tt == 0) ? accw[g_ * 4] : (tt == 1) ? accw[g_ * 4 + 1]
                : (tt == 2) ? accw[g_ * 4 + 2] : accw[g_ * 4 + 3];
        atomicAdd(&wout[b * 2048 + n0 + t * 16 + r_], v);
    }
}

// ---------------- top-k + softmax + sorted indices, one wave per (b,route) --
__global__ void topk_kernel(const float* __restrict__ w, float* __restrict__ out)
{
    const int lane = threadIdx.x;
    const int blk = blockIdx.x;          // 0..39
    const int b = blk / 5;
    const int route = blk % 5;

    const int segoff[5] = {0, 512, 768, 1280, 1792};
    const int seglen[5] = {512, 256, 512, 512, 256};
    const int kk[5]     = {64, 32, 64, 64, 32};
    const int soff[5]   = {0, 64, 96, 160, 224};
    const int ibase[5]  = {2048, 2560, 2816, 3328, 3840};

    const int L = seglen[route];
    const int K = kk[route];
    const int nv = L >> 6;               // 4 or 8 values per lane

    float v[8];
    #pragma unroll
    for (int i = 0; i < 8; ++i) {
        v[i] = -INFINITY;
        if (i < nv) v[i] = w[b * 2048 + segoff[route] + lane + 64 * i];
    }

    float selv = 0.f; int seli = 0;
    for (int it = 0; it < K; ++it) {
        float bv = -INFINITY; int bi = 0x7fffffff;
        #pragma unroll
        for (int i = 0; i < 8; ++i) {
            int li = lane + 64 * i;
            if (v[i] > bv || (v[i] == bv && li < bi)) { bv = v[i]; bi = li; }
        }
        for (int d = 1; d < 64; d <<= 1) {
            float ov = __shfl_xor(bv, d);
            int   oi = __shfl_xor(bi, d);
            if (ov > bv || (ov == bv && oi < bi)) { bv = ov; bi = oi; }
        }
        if (lane == it) { selv = bv; seli = bi; }
        #pragma unroll
        for (int i = 0; i < 8; ++i)
            if ((bi >> 6) == i && (bi & 63) == lane) v[i] = -INFINITY;
    }

    float m = __shfl(selv, 0);
    float e = (lane < K) ? __expf(selv - m) : 0.f;
    float s = e;
    for (int d = 1; d < 64; d <<= 1) s += __shfl_xor(s, d);
    if (lane < K) out[b * 256 + soff[route] + lane] = e / s;

    int rank = 0;
    for (int j = 0; j < K; ++j) {
        int oj = __shfl(seli, j);
        if (oj < seli) rank++;
    }
    if (lane < K) out[ibase[route] + b * K + rank] = (float)seli;
}

extern "C" void kernel_launch(void* const* d_in, const int* in_sizes, int n_in,
                              void* d_out, int out_size, void* d_ws, size_t ws_size,
                              hipStream_t stream)
{
    const float* x        = (const float*)d_in[0];
    const float* imp      = (const float*)d_in[1];
    const float* proj_w   = (const float*)d_in[2];
    const float* proj_b   = (const float*)d_in[3];
    const float* emb      = (const float*)d_in[4];
    const float* emb_rel  = (const float*)d_in[5];
    const float* ema_qk   = (const float*)d_in[6];
    const float* ema_v    = (const float*)d_in[7];
    const float* ema_rel  = (const float*)d_in[8];
    const float* ema_val  = (const float*)d_in[9];
    float* out = (float*)d_out;

    float* invn  = (float*)d_ws;                       // 2048 f32
    float* bonus = invn + 2048;                        // 2048 f32
    float* wacc  = bonus + 2048;                       // 16384 f32
    unsigned short* wp = (unsigned short*)(wacc + 16384);  // 3*PB u16
    unsigned short* bp = wp + 3 * PB;                  // 3*PB u16
    unsigned short* hs = bp + 3 * PB;                  // 3*PH u16 (6 MB)

    prep_kernel<<<32, 64, 0, stream>>>(emb, emb_rel, ema_qk, ema_v, ema_rel, ema_val, invn, bonus, wacc);
    wtpack3_kernel<<<64, 256, 0, stream>>>(proj_w, wp);
    embpack_kernel<<<64, 256, 0, stream>>>(emb, emb_rel, bp);
    proj_kernel<<<512, 512, 0, stream>>>(x, wp, proj_b, hs);
    route_kernel<<<512, 512, 0, stream>>>(hs, bp, imp, invn, bonus, wacc);
    topk_kernel<<<40, 64, 0, stream>>>(wacc, out);
}